// Round 1
// baseline (157.619 us; speedup 1.0000x reference)
//
#include <hip/hip_runtime.h>

#define NSEG 21      // labels 0..20
#define NLBL 20
#define DIM  32
#define PAD  33      // odd pad: bank = (s*33+d)%32 spreads labels across banks
#define DV   0.5f
#define DD   3.0f
#define BATCH 8

// ws float layout:
//   counts: [BATCH][NSEG]        at 0                      (168 floats)
//   sums:   [BATCH][NSEG][DIM]   at BATCH*NSEG             (5376 floats)
//   vsum:   [BATCH][NSEG]        at BATCH*NSEG*(1+DIM)     (168 floats)
#define WS_SUM_OFF  (BATCH * NSEG)
#define WS_VS_OFF   (BATCH * NSEG + BATCH * NSEG * DIM)
#define WS_TOTAL_F  (BATCH * NSEG + BATCH * NSEG * DIM + BATCH * NSEG)

__global__ __launch_bounds__(256)
void k_sums(const float* __restrict__ emb, const int* __restrict__ seg,
            float* __restrict__ ws, int N) {
  __shared__ float s_sum[NSEG * PAD];
  __shared__ float s_cnt[NSEG];
  const int tid = threadIdx.x;
  const int b = blockIdx.y;
  for (int i = tid; i < NSEG * PAD; i += 256) s_sum[i] = 0.f;
  if (tid < NSEG) s_cnt[tid] = 0.f;
  __syncthreads();

  const int n0 = blockIdx.x * 1024 + tid * 4;
  const size_t base = (size_t)b * DIM * N;
  const int4 s4 = *reinterpret_cast<const int4*>(seg + (size_t)b * N + n0);
  atomicAdd(&s_cnt[s4.x], 1.f);
  atomicAdd(&s_cnt[s4.y], 1.f);
  atomicAdd(&s_cnt[s4.z], 1.f);
  atomicAdd(&s_cnt[s4.w], 1.f);
  const int ax = s4.x * PAD, ay = s4.y * PAD, az = s4.z * PAD, aw = s4.w * PAD;
  #pragma unroll 8
  for (int d = 0; d < DIM; ++d) {
    const float4 e = *reinterpret_cast<const float4*>(emb + base + (size_t)d * N + n0);
    atomicAdd(&s_sum[ax + d], e.x);
    atomicAdd(&s_sum[ay + d], e.y);
    atomicAdd(&s_sum[az + d], e.z);
    atomicAdd(&s_sum[aw + d], e.w);
  }
  __syncthreads();
  float* gc = ws + b * NSEG;
  float* gs = ws + WS_SUM_OFF + b * NSEG * DIM;
  for (int i = tid; i < NSEG * DIM; i += 256)
    atomicAdd(&gs[i], s_sum[(i >> 5) * PAD + (i & 31)]);
  if (tid < NSEG) atomicAdd(&gc[tid], s_cnt[tid]);
}

__global__ __launch_bounds__(256)
void k_var(const float* __restrict__ emb, const int* __restrict__ seg,
           float* __restrict__ ws, int N) {
  __shared__ float s_m[NSEG * PAD];
  __shared__ float s_v[NSEG];
  const int tid = threadIdx.x;
  const int b = blockIdx.y;
  const float* gc = ws + b * NSEG;
  const float* gs = ws + WS_SUM_OFF + b * NSEG * DIM;
  for (int i = tid; i < NSEG * DIM; i += 256) {
    const int s = i >> 5, d = i & 31;
    s_m[s * PAD + d] = gs[i] / fmaxf(gc[s], 1.f);
  }
  if (tid < NSEG) s_v[tid] = 0.f;
  __syncthreads();

  const int n0 = blockIdx.x * 1024 + tid * 4;
  const size_t base = (size_t)b * DIM * N;
  const int4 s4 = *reinterpret_cast<const int4*>(seg + (size_t)b * N + n0);
  const int ax = s4.x * PAD, ay = s4.y * PAD, az = s4.z * PAD, aw = s4.w * PAD;
  float q0 = 0.f, q1 = 0.f, q2 = 0.f, q3 = 0.f;
  #pragma unroll 8
  for (int d = 0; d < DIM; ++d) {
    const float4 e = *reinterpret_cast<const float4*>(emb + base + (size_t)d * N + n0);
    float t;
    t = e.x - s_m[ax + d]; q0 += t * t;
    t = e.y - s_m[ay + d]; q1 += t * t;
    t = e.z - s_m[az + d]; q2 += t * t;
    t = e.w - s_m[aw + d]; q3 += t * t;
  }
  if (s4.x > 0) { const float r = sqrtf(q0) - DV; if (r > 0.f) atomicAdd(&s_v[s4.x], r * r); }
  if (s4.y > 0) { const float r = sqrtf(q1) - DV; if (r > 0.f) atomicAdd(&s_v[s4.y], r * r); }
  if (s4.z > 0) { const float r = sqrtf(q2) - DV; if (r > 0.f) atomicAdd(&s_v[s4.z], r * r); }
  if (s4.w > 0) { const float r = sqrtf(q3) - DV; if (r > 0.f) atomicAdd(&s_v[s4.w], r * r); }
  __syncthreads();
  float* gv = ws + WS_VS_OFF + b * NSEG;
  if (tid < NSEG) atomicAdd(&gv[tid], s_v[tid]);
}

__global__ __launch_bounds__(256)
void k_final(const float* __restrict__ ws, float* __restrict__ out) {
  __shared__ float s_m[NLBL * PAD];
  __shared__ float s_cnt[NSEG];
  __shared__ int   s_p[NLBL];
  __shared__ float s_var, s_dl;
  const int tid = threadIdx.x;
  float acc_v = 0.f, acc_d = 0.f;
  for (int b = 0; b < BATCH; ++b) {
    const float* gc = ws + b * NSEG;
    const float* gs = ws + WS_SUM_OFF + b * NSEG * DIM;
    const float* gv = ws + WS_VS_OFF + b * NSEG;
    __syncthreads();                       // protect reuse across batches
    if (tid < NSEG) s_cnt[tid] = gc[tid];
    if (tid == 0) { s_var = 0.f; s_dl = 0.f; }
    __syncthreads();
    for (int i = tid; i < NLBL * DIM; i += 256) {
      const int l = i >> 5, d = i & 31;    // l = 0..19 -> label l+1
      s_m[l * PAD + d] = gs[(l + 1) * DIM + d] / fmaxf(s_cnt[l + 1], 1.f);
    }
    if (tid < NLBL) s_p[tid] = (s_cnt[tid + 1] > 0.f) ? 1 : 0;
    if (tid < NLBL && s_cnt[tid + 1] > 0.f)
      atomicAdd(&s_var, gv[tid + 1] / s_cnt[tid + 1]);
    __syncthreads();                       // s_m / s_p ready
    float dl = 0.f;
    for (int p = tid; p < NLBL * NLBL; p += 256) {
      const int i = p / NLBL, j = p % NLBL;
      if (i != j && s_p[i] && s_p[j]) {
        float sq = 0.f;
        #pragma unroll
        for (int d = 0; d < DIM; ++d) {
          const float t = s_m[i * PAD + d] - s_m[j * PAD + d];
          sq += t * t;
        }
        const float r = DD - sqrtf(sq);
        if (r > 0.f) dl += r * r;
      }
    }
    atomicAdd(&s_dl, dl);
    __syncthreads();
    if (tid == 0) {
      float nl = 0.f;
      for (int l = 0; l < NLBL; ++l) nl += (float)s_p[l];
      acc_v += (nl > 0.f) ? (s_var / nl) : 0.f;
      acc_d += (nl > 1.f) ? (s_dl / fmaxf(nl * (nl - 1.f), 1.f) * 0.5f) : 0.f;
    }
  }
  if (tid == 0) {
    out[0] = acc_v / (float)BATCH;
    out[1] = acc_d / (float)BATCH;
    out[2] = 0.f;
  }
}

extern "C" void kernel_launch(void* const* d_in, const int* in_sizes, int n_in,
                              void* d_out, int out_size, void* d_ws, size_t ws_size,
                              hipStream_t stream) {
  const float* emb = (const float*)d_in[0];
  const int*   seg = (const int*)d_in[1];
  float* out = (float*)d_out;
  float* ws  = (float*)d_ws;
  const int N = in_sizes[1] / BATCH;   // 65536

  hipMemsetAsync(d_ws, 0, WS_TOTAL_F * sizeof(float), stream);

  dim3 grid(N / 1024, BATCH);
  k_sums<<<grid, 256, 0, stream>>>(emb, seg, ws, N);
  k_var <<<grid, 256, 0, stream>>>(emb, seg, ws, N);
  k_final<<<1, 256, 0, stream>>>(ws, out);
}